// Round 16
// baseline (888.613 us; speedup 1.0000x reference)
//
#include <hip/hip_runtime.h>
#include <math.h>
#include <stdint.h>

#define NPOS  32768
#define LOG2N 15
#define BATCH 8
#define TOTAL (BATCH * NPOS)          // 262144 positions
#define HE    ((size_t)16 * TOTAL)    // one fp32 h buffer, elements (16 MiB)
#define HBFE  ((size_t)16 * TOTAL)    // one bf16 H buffer, elements (8 MiB)
#define MW    2560                    // mega LDS window (floats per channel)
#define WIN   1536                    // halo slots left of owned region
#define MP    1024                    // owned positions per mega block

typedef __attribute__((ext_vector_type(8))) short short8v;  // 8 bf16 = 4 VGPR
typedef __attribute__((ext_vector_type(4))) float f32x4;    // MFMA C/D

__device__ __forceinline__ float fast_tanh(float x) {
    float t = __expf(-2.f * x);
    return fmaf(2.f, __builtin_amdgcn_rcpf(1.f + t), -1.f);
}
__device__ __forceinline__ float fast_sigmoid(float x) {
    return __builtin_amdgcn_rcpf(1.f + __expf(-x));
}
__device__ __forceinline__ unsigned short bf16rne(float x) {
    unsigned u = __float_as_uint(x);
    u = (u + 0x7fffu + ((u >> 16) & 1u)) >> 16;
    return (unsigned short)u;
}
__device__ __forceinline__ void store_bf_row(unsigned short* __restrict__ bf,
                                             int t, const float* w)
{
    unsigned pk[8];
#pragma unroll
    for (int q = 0; q < 8; ++q)
        pk[q] = (unsigned)bf16rne(w[2 * q]) | ((unsigned)bf16rne(w[2 * q + 1]) << 16);
    uint4* ob = (uint4*)(bf + (size_t)t * 16);
    ob[0] = make_uint4(pk[0], pk[1], pk[2], pk[3]);
    ob[1] = make_uint4(pk[4], pk[5], pk[6], pk[7]);
}

// ================= megakernel: all 18 live layers, LDS-resident ============
// 256 blocks x 256 thr, 1 block/CU (160 KB dynamic LDS). Block owns positions
// [base, base+1024); LDS window hsh[16][2560] covers [base-1536, base+1024).
// Per layer: compute shrinking region right-to-left in 512-pos chunks; one
// barrier per chunk (reads of chunk k+1 never touch writes of chunk k).
// fp32 ladder (same math as R10/R15); bf16 H_i snapshots -> global for final.
__global__ __launch_bounds__(256) void mega_layers(
    const int* __restrict__ x_int,
    const float* __restrict__ W0, const float* __restrict__ b0,
    const float* __restrict__ Wf, const float* __restrict__ bfv,
    const float* __restrict__ Wg, const float* __restrict__ bgv,
    unsigned short* __restrict__ Hbf)
{
    extern __shared__ float hsh[];      // [16][MW]
    const int tid  = threadIdx.x;
    const int base = blockIdx.x * MP;

    // ---- init h0 over the whole window (t<0 slots -> 0, never consumed)
    for (int x = tid; x < MW; x += 256) {
        int t = base - WIN + x;
        float h0[16];
        if (t < 0) {
#pragma unroll
            for (int c = 0; c < 16; ++c) h0[c] = 0.f;
        } else {
            int n = t & (NPOS - 1);
            const float sc = 1.f / 32768.f;
            float xs  = (n >= 1) ? (float)x_int[t - 1] * sc : 0.f;
            float xsp = (n >= 2) ? (float)x_int[t - 2] * sc : 0.f;
#pragma unroll
            for (int c = 0; c < 16; ++c)
                h0[c] = xs + W0[c * 2 + 0] * xsp + W0[c * 2 + 1] * xs + b0[c];
        }
#pragma unroll
        for (int c = 0; c < 16; ++c) hsh[c * MW + x] = h0[c];
        if (x >= WIN) store_bf_row(Hbf, t, h0);     // H_0 snapshot (owned)
    }
    __syncthreads();

    const int dd[18]   = {2,4,8,16,32,64,128,256,512,1,2,4,8,16,32,64,128,256};
    const int remv[18] = {1531,1527,1519,1503,1471,1407,1279,1023,511,
                          510,508,504,496,480,448,384,256,0};

#pragma unroll 1
    for (int i = 0; i < 18; ++i) {
        const int d   = dd[i];
        const int xlo = (WIN - remv[i]) & ~1;        // reads stay >= xlo-d >= 2
        const int nch = (MW - xlo + 511) >> 9;
        const float* wf  = Wf  + (size_t)i * 512;
        const float* wg  = Wg  + (size_t)i * 512;
        const float* bfL = bfv + i * 16;
        const float* bgL = bgv + i * 16;
        unsigned short* Ho = Hbf + (size_t)(i + 1) * HBFE;

#pragma unroll 1
        for (int k = 0; k < nch; ++k) {
            int x0 = (MW - (k + 1) * 512) + tid * 2;
            bool act = (x0 >= xlo);
            int t0 = base - WIN + x0;
            float nhx[16], nhy[16];

            if (act) {
                int n0 = t0 & (NPOS - 1);            // t0<0 -> garbage region, never consumed
                float2 hc[16], hp[16];
#pragma unroll
                for (int ic = 0; ic < 16; ++ic)
                    hc[ic] = *(const float2*)(&hsh[ic * MW + x0]);

                if (d == 1) {
                    bool v = (n0 >= 1);
#pragma unroll
                    for (int ic = 0; ic < 16; ++ic) {
                        float xv = hsh[ic * MW + x0 - 1];
                        hp[ic].x = v ? xv : 0.f;
                        hp[ic].y = hc[ic].x;
                    }
                } else {
                    bool v = (n0 >= d);
#pragma unroll
                    for (int ic = 0; ic < 16; ++ic) {
                        float2 xv = *(const float2*)(&hsh[ic * MW + x0 - d]);
                        hp[ic].x = v ? xv.x : 0.f;
                        hp[ic].y = v ? xv.y : 0.f;
                    }
                }

#pragma unroll
                for (int c = 0; c < 16; ++c) {
                    float fax = bfL[c], fay = bfL[c];
                    float gax = bgL[c], gay = bgL[c];
#pragma unroll
                    for (int ic = 0; ic < 16; ++ic) {
                        float wf0 = wf[(c * 16 + ic) * 2 + 0];
                        float wf1 = wf[(c * 16 + ic) * 2 + 1];
                        float wg0 = wg[(c * 16 + ic) * 2 + 0];
                        float wg1 = wg[(c * 16 + ic) * 2 + 1];
                        fax = fmaf(wf0, hp[ic].x, fax);
                        fax = fmaf(wf1, hc[ic].x, fax);
                        fay = fmaf(wf0, hp[ic].y, fay);
                        fay = fmaf(wf1, hc[ic].y, fay);
                        gax = fmaf(wg0, hp[ic].x, gax);
                        gax = fmaf(wg1, hc[ic].x, gax);
                        gay = fmaf(wg0, hp[ic].y, gay);
                        gay = fmaf(wg1, hc[ic].y, gay);
                    }
                    nhx[c] = fmaf(fast_tanh(fax), fast_sigmoid(gax), hc[c].x);
                    nhy[c] = fmaf(fast_tanh(fay), fast_sigmoid(gay), hc[c].y);
                }
            }

            __syncthreads();   // all reads of this chunk done before any write

            if (act) {
#pragma unroll
                for (int c = 0; c < 16; ++c)
                    *(float2*)(&hsh[c * MW + x0]) = make_float2(nhx[c], nhy[c]);
                if (x0 >= WIN) {
                    store_bf_row(Ho, t0,     nhx);
                    store_bf_row(Ho, t0 + 1, nhy);
                }
            }
        }
    }
}

// ================= final: MFMA skip-sum (bf16 H) + agg + MFMA logits =======
// (verbatim R12 final_kernel_ds4 — validated ~210 µs)
__global__ __launch_bounds__(256, 2) void final_kernel_ds4(
    const unsigned short* __restrict__ Hbf,
    const float* __restrict__ Wsk,  const float* __restrict__ bskv,
    const float* __restrict__ Wagg, const float* __restrict__ bagg,
    const float* __restrict__ Wout, const float* __restrict__ bout,
    float* __restrict__ out)
{
    __shared__ float sv_lds[64][33];
    __shared__ unsigned short agg_bu[64 * 64];
    __shared__ float red_m[64][5];
    __shared__ float red_s[64][5];
    __shared__ float bsum[32];

    int tid  = threadIdx.x;
    int lane = tid & 63;
    int w    = tid >> 6;
    int posG = blockIdx.x * 64;
    int b    = posG >> LOG2N;
    int nb   = posG & (NPOS - 1);

    int lr = lane & 15;
    int lg = lane >> 4;

    if (tid < 32) {
        float s = 0.f;
#pragma unroll 1
        for (int i = 0; i < 19; ++i) s += bskv[i * 32 + tid];
        bsum[tid] = s;
    }

    int posGlob = posG + w * 16 + lr;

    f32x4 dsk0 = {0.f, 0.f, 0.f, 0.f};
    f32x4 dsk1 = {0.f, 0.f, 0.f, 0.f};

#pragma unroll
    for (int kt = 0; kt < 10; ++kt) {
        int i   = kt * 2 + (lg >> 1);
        int ic0 = (lg & 1) * 8;
        short8v bfr = {0, 0, 0, 0, 0, 0, 0, 0};
        short8v af0 = {0, 0, 0, 0, 0, 0, 0, 0};
        short8v af1 = {0, 0, 0, 0, 0, 0, 0, 0};
        if (i < 19) {
            bfr = *(const short8v*)(Hbf + (size_t)i * HBFE + (size_t)posGlob * 16 + ic0);

            const float4* wp0 = (const float4*)(Wsk + (size_t)i * 512 + (0 * 16 + lr) * 16 + ic0);
            const float4* wp1 = (const float4*)(Wsk + (size_t)i * 512 + (1 * 16 + lr) * 16 + ic0);
            float4 a0 = wp0[0], a1 = wp0[1];
            float4 c0v = wp1[0], c1v = wp1[1];
            af0[0] = (short)bf16rne(a0.x); af0[1] = (short)bf16rne(a0.y);
            af0[2] = (short)bf16rne(a0.z); af0[3] = (short)bf16rne(a0.w);
            af0[4] = (short)bf16rne(a1.x); af0[5] = (short)bf16rne(a1.y);
            af0[6] = (short)bf16rne(a1.z); af0[7] = (short)bf16rne(a1.w);
            af1[0] = (short)bf16rne(c0v.x); af1[1] = (short)bf16rne(c0v.y);
            af1[2] = (short)bf16rne(c0v.z); af1[3] = (short)bf16rne(c0v.w);
            af1[4] = (short)bf16rne(c1v.x); af1[5] = (short)bf16rne(c1v.y);
            af1[6] = (short)bf16rne(c1v.z); af1[7] = (short)bf16rne(c1v.w);
        }
        dsk0 = __builtin_amdgcn_mfma_f32_16x16x32_bf16(af0, bfr, dsk0, 0, 0, 0);
        dsk1 = __builtin_amdgcn_mfma_f32_16x16x32_bf16(af1, bfr, dsk1, 0, 0, 0);
    }

    __syncthreads();

    {
        int posL = w * 16 + lr;
#pragma unroll
        for (int r = 0; r < 4; ++r) {
            int sc0 = 0 * 16 + lg * 4 + r;
            int sc1 = 1 * 16 + lg * 4 + r;
            sv_lds[posL][sc0] = fmaxf(dsk0[r] + bsum[sc0], 0.f);
            sv_lds[posL][sc1] = fmaxf(dsk1[r] + bsum[sc1], 0.f);
        }
    }
    __syncthreads();

    {
        float sv[32];
#pragma unroll
        for (int sch = 0; sch < 32; ++sch) sv[sch] = sv_lds[lane][sch];

        float r16[16];
#pragma unroll
        for (int a = 0; a < 16; ++a) {
            int ac = w * 16 + a;
            float acc = bagg[ac];
#pragma unroll
            for (int sch = 0; sch < 32; ++sch)
                acc = fmaf(Wagg[ac * 32 + sch], sv[sch], acc);
            r16[a] = fmaxf(acc, 0.f);
        }
#pragma unroll
        for (int q = 0; q < 8; ++q) {
            unsigned pk = (unsigned)bf16rne(r16[2 * q]) |
                          ((unsigned)bf16rne(r16[2 * q + 1]) << 16);
            int icbyte = (w * 16 + 2 * q) * 2;
            int addr   = lane * 128 + (icbyte ^ ((lane & 7) << 4));
            *(unsigned*)(&agg_bu[addr >> 1]) = pk;
        }
    }
    __syncthreads();

    int c0 = w * 64;
    short8v afr[4][2];
#pragma unroll
    for (int ct = 0; ct < 4; ++ct) {
#pragma unroll
        for (int kf = 0; kf < 2; ++kf) {
            int cls = c0 + ct * 16 + lr;
            int k0  = kf * 32 + lg * 8;
            const float4* wp = (const float4*)(Wout + (size_t)cls * 64 + k0);
            float4 w0 = wp[0], w1 = wp[1];
            short8v af;
            af[0] = (short)bf16rne(w0.x); af[1] = (short)bf16rne(w0.y);
            af[2] = (short)bf16rne(w0.z); af[3] = (short)bf16rne(w0.w);
            af[4] = (short)bf16rne(w1.x); af[5] = (short)bf16rne(w1.y);
            af[6] = (short)bf16rne(w1.z); af[7] = (short)bf16rne(w1.w);
            afr[ct][kf] = af;
        }
    }

    f32x4 acc[4][4];
#pragma unroll
    for (int pt = 0; pt < 4; ++pt) {
        int pos = pt * 16 + lr;
        int sw  = (pos & 7) << 4;
        const short8v* bp0 = (const short8v*)(&agg_bu[(pos * 128 + ((0 * 64 + lg * 16) ^ sw)) >> 1]);
        const short8v* bp1 = (const short8v*)(&agg_bu[(pos * 128 + ((1 * 64 + lg * 16) ^ sw)) >> 1]);
        short8v bf0 = *bp0;
        short8v bf1 = *bp1;
#pragma unroll
        for (int ct = 0; ct < 4; ++ct) {
            f32x4 c;
#pragma unroll
            for (int r = 0; r < 4; ++r) c[r] = bout[c0 + ct * 16 + lg * 4 + r];
            c = __builtin_amdgcn_mfma_f32_16x16x32_bf16(afr[ct][0], bf0, c, 0, 0, 0);
            c = __builtin_amdgcn_mfma_f32_16x16x32_bf16(afr[ct][1], bf1, c, 0, 0, 0);
            acc[pt][ct] = c;
        }
    }

#pragma unroll
    for (int pt = 0; pt < 4; ++pt) {
        float m = -1e30f;
#pragma unroll
        for (int ct = 0; ct < 4; ++ct)
#pragma unroll
            for (int r = 0; r < 4; ++r) m = fmaxf(m, acc[pt][ct][r]);
        m = fmaxf(m, __shfl_xor(m, 16));
        m = fmaxf(m, __shfl_xor(m, 32));
        float s = 0.f;
#pragma unroll
        for (int ct = 0; ct < 4; ++ct)
#pragma unroll
            for (int r = 0; r < 4; ++r) s += __expf(acc[pt][ct][r] - m);
        s += __shfl_xor(s, 16);
        s += __shfl_xor(s, 32);
        int pos = pt * 16 + lr;
        red_m[pos][w] = m;
        red_s[pos][w] = s;
    }
    __syncthreads();

#pragma unroll
    for (int pt = 0; pt < 4; ++pt) {
        int pos = pt * 16 + lr;
        float M = fmaxf(fmaxf(red_m[pos][0], red_m[pos][1]),
                        fmaxf(red_m[pos][2], red_m[pos][3]));
        float S = 0.f;
#pragma unroll
        for (int k = 0; k < 4; ++k) S += red_s[pos][k] * __expf(red_m[pos][k] - M);
        float logZ = M + __logf(S);

        int n = nb + pos;
#pragma unroll
        for (int ct = 0; ct < 4; ++ct) {
#pragma unroll
            for (int r = 0; r < 4; ++r) {
                int cls = c0 + ct * 16 + lg * 4 + r;
                out[((size_t)(b * 256 + cls)) * NPOS + n] = acc[pt][ct][r] - logZ;
            }
        }
    }
}

// ======================================================================
// R15 fallback path (proven 676 µs): init2 + lds/ns layers + ds2 final
// ======================================================================
__global__ __launch_bounds__(256) void init_kernel2(
    const int* __restrict__ x_int, const float* __restrict__ W0,
    const float* __restrict__ b0, float* __restrict__ h)
{
    int t0 = (blockIdx.x * 256 + threadIdx.x) * 2;
    int n0 = t0 & (NPOS - 1);
    const float sc = 1.f / 32768.f;
    float xs0  = (n0 >= 1) ? (float)x_int[t0 - 1] * sc : 0.f;
    float xs1  = (float)x_int[t0] * sc;
    float xsp0 = (n0 >= 2) ? (float)x_int[t0 - 2] * sc : 0.f;
    float xsp1 = xs0;
#pragma unroll
    for (int c = 0; c < 16; ++c) {
        float2 o;
        o.x = xs0 + W0[c * 2 + 0] * xsp0 + W0[c * 2 + 1] * xs0 + b0[c];
        o.y = xs1 + W0[c * 2 + 0] * xsp1 + W0[c * 2 + 1] * xs1 + b0[c];
        *(float2*)(h + (size_t)c * TOTAL + t0) = o;
    }
}

__global__ __launch_bounds__(256, 2) void layer_kernel_ns(
    const float* __restrict__ hIn, float* __restrict__ hOut,
    const float* __restrict__ wf, const float* __restrict__ bfv,
    const float* __restrict__ wg, const float* __restrict__ bgv,
    int d)
{
    int t0 = (blockIdx.x * 256 + threadIdx.x) * 2;
    int n0 = t0 & (NPOS - 1);

    float2 hc[16], hp[16];
#pragma unroll
    for (int ic = 0; ic < 16; ++ic)
        hc[ic] = *(const float2*)(hIn + (size_t)ic * TOTAL + t0);

    {
        bool v = (n0 >= d);
        int tm = v ? (t0 - d) : t0;
#pragma unroll
        for (int ic = 0; ic < 16; ++ic) {
            float2 x = *(const float2*)(hIn + (size_t)ic * TOTAL + tm);
            hp[ic].x = v ? x.x : 0.f;
            hp[ic].y = v ? x.y : 0.f;
        }
    }

    float2 fa[16], ga[16];
#pragma unroll
    for (int c = 0; c < 16; ++c) {
        fa[c].x = fa[c].y = bfv[c];
        ga[c].x = ga[c].y = bgv[c];
    }
#pragma unroll
    for (int c = 0; c < 16; ++c) {
#pragma unroll
        for (int ic = 0; ic < 16; ++ic) {
            float wf0 = wf[(c * 16 + ic) * 2 + 0];
            float wf1 = wf[(c * 16 + ic) * 2 + 1];
            float wg0 = wg[(c * 16 + ic) * 2 + 0];
            float wg1 = wg[(c * 16 + ic) * 2 + 1];
            fa[c].x = fmaf(wf0, hp[ic].x, fa[c].x);
            fa[c].x = fmaf(wf1, hc[ic].x, fa[c].x);
            fa[c].y = fmaf(wf0, hp[ic].y, fa[c].y);
            fa[c].y = fmaf(wf1, hc[ic].y, fa[c].y);
            ga[c].x = fmaf(wg0, hp[ic].x, ga[c].x);
            ga[c].x = fmaf(wg1, hc[ic].x, ga[c].x);
            ga[c].y = fmaf(wg0, hp[ic].y, ga[c].y);
            ga[c].y = fmaf(wg1, hc[ic].y, ga[c].y);
        }
    }

#pragma unroll
    for (int c = 0; c < 16; ++c) {
        float2 o;
        o.x = fmaf(fast_tanh(fa[c].x), fast_sigmoid(ga[c].x), hc[c].x);
        o.y = fmaf(fast_tanh(fa[c].y), fast_sigmoid(ga[c].y), hc[c].y);
        *(float2*)(hOut + (size_t)c * TOTAL + t0) = o;
    }
}

__global__ __launch_bounds__(256, 2) void layer_kernel_lds(
    const float* __restrict__ hIn, float* __restrict__ hOut,
    const float* __restrict__ wf, const float* __restrict__ bfv,
    const float* __restrict__ wg, const float* __restrict__ bgv,
    int ld)
{
    __shared__ float hsh2[16 * 768];

    int d    = 1 << ld;
    int dpad = (d < 4) ? 4 : d;
    int S    = 512 + dpad;
    int base = blockIdx.x * 512;

    {
        int q = threadIdx.x;
#pragma unroll
        for (int r = 0; r < 8; ++r, q += 256) {
            int ic = q >> 7;
            int w4 = q & 127;
            float4 v = *(const float4*)(hIn + (size_t)ic * TOTAL + base + w4 * 4);
            *(float4*)(&hsh2[ic * S + dpad + w4 * 4]) = v;
        }
    }
    for (int idx = threadIdx.x; idx < (16 << ld); idx += 256) {
        int ic = idx >> ld;
        int j  = idx & (d - 1);
        int t  = base - d + j;
        int tc = (t < 0) ? 0 : t;
        hsh2[ic * S + (dpad - d) + j] = hIn[(size_t)ic * TOTAL + tc];
    }
    __syncthreads();

    int t0 = base + threadIdx.x * 2;
    int n0 = t0 & (NPOS - 1);
    int jj = dpad + threadIdx.x * 2;

    float2 hc[16], hp[16];
#pragma unroll
    for (int ic = 0; ic < 16; ++ic)
        hc[ic] = *(const float2*)(&hsh2[ic * S + jj]);

    if (d == 1) {
        bool v = (n0 >= 1);
#pragma unroll
        for (int ic = 0; ic < 16; ++ic) {
            float x = hsh2[ic * S + jj - 1];
            hp[ic].x = v ? x : 0.f;
            hp[ic].y = hc[ic].x;
        }
    } else {
        bool v = (n0 >= d);
#pragma unroll
        for (int ic = 0; ic < 16; ++ic) {
            float2 x = *(const float2*)(&hsh2[ic * S + jj - d]);
            hp[ic].x = v ? x.x : 0.f;
            hp[ic].y = v ? x.y : 0.f;
        }
    }

    float2 fa[16], ga[16];
#pragma unroll
    for (int c = 0; c < 16; ++c) {
        fa[c].x = fa[c].y = bfv[c];
        ga[c].x = ga[c].y = bgv[c];
    }
#pragma unroll
    for (int c = 0; c < 16; ++c) {
#pragma unroll
        for (int ic = 0; ic < 16; ++ic) {
            float wf0 = wf[(c * 16 + ic) * 2 + 0];
            float wf1 = wf[(c * 16 + ic) * 2 + 1];
            float wg0 = wg[(c * 16 + ic) * 2 + 0];
            float wg1 = wg[(c * 16 + ic) * 2 + 1];
            fa[c].x = fmaf(wf0, hp[ic].x, fa[c].x);
            fa[c].x = fmaf(wf1, hc[ic].x, fa[c].x);
            fa[c].y = fmaf(wf0, hp[ic].y, fa[c].y);
            fa[c].y = fmaf(wf1, hc[ic].y, fa[c].y);
            ga[c].x = fmaf(wg0, hp[ic].x, ga[c].x);
            ga[c].x = fmaf(wg1, hc[ic].x, ga[c].x);
            ga[c].y = fmaf(wg0, hp[ic].y, ga[c].y);
            ga[c].y = fmaf(wg1, hc[ic].y, ga[c].y);
        }
    }

#pragma unroll
    for (int c = 0; c < 16; ++c) {
        float2 o;
        o.x = fmaf(fast_tanh(fa[c].x), fast_sigmoid(ga[c].x), hc[c].x);
        o.y = fmaf(fast_tanh(fa[c].y), fast_sigmoid(ga[c].y), hc[c].y);
        *(float2*)(hOut + (size_t)c * TOTAL + t0) = o;
    }
}

__global__ __launch_bounds__(256, 2) void final_kernel_ds2(
    const float* __restrict__ Hbase,
    const float* __restrict__ Wsk,  const float* __restrict__ bskv,
    const float* __restrict__ Wagg, const float* __restrict__ bagg,
    const float* __restrict__ Wout, const float* __restrict__ bout,
    float* __restrict__ out)
{
    __shared__ float sv_lds[64][33];
    __shared__ unsigned short agg_bu[64 * 64];
    __shared__ float red_m[64][5];
    __shared__ float red_s[64][5];
    __shared__ float bsum[32];

    int tid  = threadIdx.x;
    int lane = tid & 63;
    int w    = tid >> 6;
    int posG = blockIdx.x * 64;
    int b    = posG >> LOG2N;
    int nb   = posG & (NPOS - 1);

    int lr = lane & 15;
    int lg = lane >> 4;

    if (tid < 32) {
        float s = 0.f;
#pragma unroll 1
        for (int i = 0; i < 19; ++i) s += bskv[i * 32 + tid];
        bsum[tid] = s;
    }

    int posGlob = posG + w * 16 + lr;

    f32x4 dsk0 = {0.f, 0.f, 0.f, 0.f};
    f32x4 dsk1 = {0.f, 0.f, 0.f, 0.f};

#pragma unroll
    for (int kt = 0; kt < 10; ++kt) {
        int i   = kt * 2 + (lg >> 1);
        int ic0 = (lg & 1) * 8;
        short8v bfr = {0, 0, 0, 0, 0, 0, 0, 0};
        short8v af0 = {0, 0, 0, 0, 0, 0, 0, 0};
        short8v af1 = {0, 0, 0, 0, 0, 0, 0, 0};
        if (i < 19) {
            const float* hb = Hbase + (size_t)i * HE + (size_t)ic0 * TOTAL + posGlob;
#pragma unroll
            for (int j = 0; j < 8; ++j)
                bfr[j] = (short)bf16rne(hb[(size_t)j * TOTAL]);

            const float4* wp0 = (const float4*)(Wsk + (size_t)i * 512 + (0 * 16 + lr) * 16 + ic0);
            const float4* wp1 = (const float4*)(Wsk + (size_t)i * 512 + (1 * 16 + lr) * 16 + ic0);
            float4 a0 = wp0[0], a1 = wp0[1];
            float4 c0v = wp1[0], c1v = wp1[1];
            af0[0] = (short)bf16rne(a0.x); af0[1] = (short)bf16rne(a0.y);
            af0[2] = (short)bf16rne(a0.z); af0[3] = (short)bf16rne(a0.w);
            af0[4] = (short)bf16rne(a1.x); af0[5] = (short)bf16rne(a1.y);
            af0[6] = (short)bf16rne(a1.z); af0[7] = (short)bf16rne(a1.w);
            af1[0] = (short)bf16rne(c0v.x); af1[1] = (short)bf16rne(c0v.y);
            af1[2] = (short)bf16rne(c0v.z); af1[3] = (short)bf16rne(c0v.w);
            af1[4] = (short)bf16rne(c1v.x); af1[5] = (short)bf16rne(c1v.y);
            af1[6] = (short)bf16rne(c1v.z); af1[7] = (short)bf16rne(c1v.w);
        }
        dsk0 = __builtin_amdgcn_mfma_f32_16x16x32_bf16(af0, bfr, dsk0, 0, 0, 0);
        dsk1 = __builtin_amdgcn_mfma_f32_16x16x32_bf16(af1, bfr, dsk1, 0, 0, 0);
    }

    __syncthreads();

    {
        int posL = w * 16 + lr;
#pragma unroll
        for (int r = 0; r < 4; ++r) {
            int sc0 = 0 * 16 + lg * 4 + r;
            int sc1 = 1 * 16 + lg * 4 + r;
            sv_lds[posL][sc0] = fmaxf(dsk0[r] + bsum[sc0], 0.f);
            sv_lds[posL][sc1] = fmaxf(dsk1[r] + bsum[sc1], 0.f);
        }
    }
    __syncthreads();

    {
        float sv[32];
#pragma unroll
        for (int sch = 0; sch < 32; ++sch) sv[sch] = sv_lds[lane][sch];

        float r16[16];
#pragma unroll
        for (int a = 0; a < 16; ++a) {
            int ac = w * 16 + a;
            float acc = bagg[ac];
#pragma unroll
            for (int sch = 0; sch < 32; ++sch)
                acc = fmaf(Wagg[ac * 32 + sch], sv[sch], acc);
            r16[a] = fmaxf(acc, 0.f);
        }
#pragma unroll
        for (int q = 0; q < 8; ++q) {
            unsigned pk = (unsigned)bf16rne(r16[2 * q]) |
                          ((unsigned)bf16rne(r16[2 * q + 1]) << 16);
            int icbyte = (w * 16 + 2 * q) * 2;
            int addr   = lane * 128 + (icbyte ^ ((lane & 7) << 4));
            *(unsigned*)(&agg_bu[addr >> 1]) = pk;
        }
    }
    __syncthreads();

    int c0 = w * 64;
    short8v afr[4][2];
#pragma unroll
    for (int ct = 0; ct < 4; ++ct) {
#pragma unroll
        for (int kf = 0; kf < 2; ++kf) {
            int cls = c0 + ct * 16 + lr;
            int k0  = kf * 32 + lg * 8;
            const float4* wp = (const float4*)(Wout + (size_t)cls * 64 + k0);
            float4 w0 = wp[0], w1 = wp[1];
            short8v af;
            af[0] = (short)bf16rne(w0.x); af[1] = (short)bf16rne(w0.y);
            af[2] = (short)bf16rne(w0.z); af[3] = (short)bf16rne(w0.w);
            af[4] = (short)bf16rne(w1.x); af[5] = (short)bf16rne(w1.y);
            af[6] = (short)bf16rne(w1.z); af[7] = (short)bf16rne(w1.w);
            afr[ct][kf] = af;
        }
    }

    f32x4 acc[4][4];
#pragma unroll
    for (int pt = 0; pt < 4; ++pt) {
        int pos = pt * 16 + lr;
        int sw  = (pos & 7) << 4;
        const short8v* bp0 = (const short8v*)(&agg_bu[(pos * 128 + ((0 * 64 + lg * 16) ^ sw)) >> 1]);
        const short8v* bp1 = (const short8v*)(&agg_bu[(pos * 128 + ((1 * 64 + lg * 16) ^ sw)) >> 1]);
        short8v bf0 = *bp0;
        short8v bf1 = *bp1;
#pragma unroll
        for (int ct = 0; ct < 4; ++ct) {
            f32x4 c;
#pragma unroll
            for (int r = 0; r < 4; ++r) c[r] = bout[c0 + ct * 16 + lg * 4 + r];
            c = __builtin_amdgcn_mfma_f32_16x16x32_bf16(afr[ct][0], bf0, c, 0, 0, 0);
            c = __builtin_amdgcn_mfma_f32_16x16x32_bf16(afr[ct][1], bf1, c, 0, 0, 0);
            acc[pt][ct] = c;
        }
    }

#pragma unroll
    for (int pt = 0; pt < 4; ++pt) {
        float m = -1e30f;
#pragma unroll
        for (int ct = 0; ct < 4; ++ct)
#pragma unroll
            for (int r = 0; r < 4; ++r) m = fmaxf(m, acc[pt][ct][r]);
        m = fmaxf(m, __shfl_xor(m, 16));
        m = fmaxf(m, __shfl_xor(m, 32));
        float s = 0.f;
#pragma unroll
        for (int ct = 0; ct < 4; ++ct)
#pragma unroll
            for (int r = 0; r < 4; ++r) s += __expf(acc[pt][ct][r] - m);
        s += __shfl_xor(s, 16);
        s += __shfl_xor(s, 32);
        int pos = pt * 16 + lr;
        red_m[pos][w] = m;
        red_s[pos][w] = s;
    }
    __syncthreads();

#pragma unroll
    for (int pt = 0; pt < 4; ++pt) {
        int pos = pt * 16 + lr;
        float M = fmaxf(fmaxf(red_m[pos][0], red_m[pos][1]),
                        fmaxf(red_m[pos][2], red_m[pos][3]));
        float S = 0.f;
#pragma unroll
        for (int k = 0; k < 4; ++k) S += red_s[pos][k] * __expf(red_m[pos][k] - M);
        float logZ = M + __logf(S);

        int n = nb + pos;
#pragma unroll
        for (int ct = 0; ct < 4; ++ct) {
#pragma unroll
            for (int r = 0; r < 4; ++r) {
                int cls = c0 + ct * 16 + lg * 4 + r;
                out[((size_t)(b * 256 + cls)) * NPOS + n] = acc[pt][ct][r] - logZ;
            }
        }
    }
}

extern "C" void kernel_launch(void* const* d_in, const int* in_sizes, int n_in,
                              void* d_out, int out_size, void* d_ws, size_t ws_size,
                              hipStream_t stream)
{
    const int*   x_int = (const int*)  d_in[0];
    const float* W0    = (const float*)d_in[1];
    const float* b0    = (const float*)d_in[2];
    const float* Wf    = (const float*)d_in[3];
    const float* bfv   = (const float*)d_in[4];
    const float* Wg    = (const float*)d_in[5];
    const float* bgv   = (const float*)d_in[6];
    const float* Wsk   = (const float*)d_in[7];
    const float* bskv  = (const float*)d_in[8];
    const float* Wagg  = (const float*)d_in[9];
    const float* bagg  = (const float*)d_in[10];
    const float* Wout  = (const float*)d_in[11];
    const float* bout  = (const float*)d_in[12];
    float* out = (float*)d_out;

    const size_t needMega  = 19 * HBFE * sizeof(unsigned short);  // 152 MiB
    const size_t needFall  = 19 * HE * sizeof(float);             // 304 MiB
    const int    MEGA_LDS  = 16 * MW * 4;                         // 163840 B

    bool megaDone = false;
    if (ws_size >= needMega) {
        hipError_t aerr = hipFuncSetAttribute(
            reinterpret_cast<const void*>(mega_layers),
            hipFuncAttributeMaxDynamicSharedMemorySize, MEGA_LDS);
        if (aerr == hipSuccess) {
            unsigned short* Hbf = (unsigned short*)d_ws;
            hipLaunchKernelGGL(mega_layers, dim3(TOTAL / MP), dim3(256),
                               MEGA_LDS, stream,
                               x_int, W0, b0, Wf, bfv, Wg, bgv, Hbf);
            if (hipGetLastError() == hipSuccess) {
                final_kernel_ds4<<<TOTAL / 64, 256, 0, stream>>>(
                    Hbf, Wsk, bskv, Wagg, bagg, Wout, bout, out);
                megaDone = true;
            }
        }
    }

    if (!megaDone && ws_size >= needFall) {
        // R15 proven path
        float* Hb = (float*)d_ws;
        const int grid2 = TOTAL / (256 * 2);

        init_kernel2<<<grid2, 256, 0, stream>>>(x_int, W0, b0, Hb);
        for (int i = 0; i < 18; ++i) {
            int ld = (i + 1) % 10;
            const float* hin = Hb + (size_t)i * HE;
            float* hout = Hb + (size_t)(i + 1) * HE;
            if (ld == 9) {
                layer_kernel_ns<<<grid2, 256, 0, stream>>>(
                    hin, hout,
                    Wf + (size_t)i * 512, bfv + (size_t)i * 16,
                    Wg + (size_t)i * 512, bgv + (size_t)i * 16, 512);
            } else {
                layer_kernel_lds<<<grid2, 256, 0, stream>>>(
                    hin, hout,
                    Wf + (size_t)i * 512, bfv + (size_t)i * 16,
                    Wg + (size_t)i * 512, bgv + (size_t)i * 16, ld);
            }
        }
        final_kernel_ds2<<<TOTAL / 64, 256, 0, stream>>>(
            Hb, Wsk, bskv, Wagg, bagg, Wout, bout, out);
    }
}

// Round 17
// 617.207 us; speedup vs baseline: 1.4397x; 1.4397x over previous
//
#include <hip/hip_runtime.h>
#include <math.h>
#include <stdint.h>

#define NPOS  32768
#define LOG2N 15
#define BATCH 8
#define TOTAL (BATCH * NPOS)          // 262144 positions
#define HE    ((size_t)16 * TOTAL)    // fp32 h buffer elements (fallback)
#define HFE   ((size_t)16 * TOTAL)    // one fp16 H buffer, elements (8 MiB)

typedef __attribute__((ext_vector_type(8))) short    short8v;  // 8 bf16
typedef __attribute__((ext_vector_type(8))) _Float16 half8v;   // 8 fp16
typedef __attribute__((ext_vector_type(4))) float    f32x4;    // MFMA C/D

__device__ __forceinline__ float fast_tanh(float x) {
    float t = __expf(-2.f * x);
    return fmaf(2.f, __builtin_amdgcn_rcpf(1.f + t), -1.f);
}
__device__ __forceinline__ float fast_sigmoid(float x) {
    return __builtin_amdgcn_rcpf(1.f + __expf(-x));
}
__device__ __forceinline__ unsigned short bf16rne(float x) {
    unsigned u = __float_as_uint(x);
    u = (u + 0x7fffu + ((u >> 16) & 1u)) >> 16;
    return (unsigned short)u;
}
__device__ __forceinline__ unsigned short f16bits(float x) {
    union { _Float16 h; unsigned short u; } cv;
    cv.h = (_Float16)x;          // RNE
    return cv.u;
}

// ======================================================================
// fp16-ladder defer-skip path. H_i = [pos][16] fp16, i = 0..18 (152 MiB ws).
// Layers read H_i, write H_{i+1}; ladder IS the snapshot. fp32 compute core.
// ======================================================================

__global__ __launch_bounds__(256) void init_f16(
    const int* __restrict__ x_int, const float* __restrict__ W0,
    const float* __restrict__ b0, _Float16* __restrict__ H0)
{
    int t0 = (blockIdx.x * 256 + threadIdx.x) * 2;
    int n0 = t0 & (NPOS - 1);
    const float sc = 1.f / 32768.f;
    float xs0  = (n0 >= 1) ? (float)x_int[t0 - 1] * sc : 0.f;
    float xs1  = (float)x_int[t0] * sc;
    float xsp0 = (n0 >= 2) ? (float)x_int[t0 - 2] * sc : 0.f;
    float xsp1 = xs0;

    half8v o[4];
#pragma unroll
    for (int c = 0; c < 16; ++c) {
        float a = xs0 + W0[c * 2 + 0] * xsp0 + W0[c * 2 + 1] * xs0 + b0[c];
        float b = xs1 + W0[c * 2 + 0] * xsp1 + W0[c * 2 + 1] * xs1 + b0[c];
        o[c >> 3][c & 7]       = (_Float16)a;   // row t0
        o[2 + (c >> 3)][c & 7] = (_Float16)b;   // row t0+1
    }
    half8v* op = (half8v*)(H0 + (size_t)t0 * 16);
    op[0] = o[0]; op[1] = o[1]; op[2] = o[2]; op[3] = o[3];
}

// ---- residual layer: fp16 in/out, fp32 core (R10-validated math) ----------
__global__ __launch_bounds__(256, 2) void layer_f16(
    const _Float16* __restrict__ hIn, _Float16* __restrict__ hOut,
    const float* __restrict__ wf, const float* __restrict__ bfv,
    const float* __restrict__ wg, const float* __restrict__ bgv,
    int d)
{
    int t0 = (blockIdx.x * 256 + threadIdx.x) * 2;
    int n0 = t0 & (NPOS - 1);

    float ra[16], rb[16], pa[16], pb[16];
    {
        const half8v* p = (const half8v*)(hIn + (size_t)t0 * 16);
        half8v v0 = p[0], v1 = p[1], v2 = p[2], v3 = p[3];
#pragma unroll
        for (int j = 0; j < 8; ++j) {
            ra[j] = (float)v0[j]; ra[8 + j] = (float)v1[j];
            rb[j] = (float)v2[j]; rb[8 + j] = (float)v3[j];
        }
    }
    if (d == 1) {
        bool v = (n0 >= 1);
        const half8v* p = (const half8v*)(hIn + (size_t)(v ? (t0 - 1) : t0) * 16);
        half8v v0 = p[0], v1 = p[1];
#pragma unroll
        for (int j = 0; j < 8; ++j) {
            pa[j]     = v ? (float)v0[j] : 0.f;
            pa[8 + j] = v ? (float)v1[j] : 0.f;
        }
#pragma unroll
        for (int c = 0; c < 16; ++c) pb[c] = ra[c];
    } else {
        bool v = (n0 >= d);
        const half8v* p = (const half8v*)(hIn + (size_t)(v ? (t0 - d) : t0) * 16);
        half8v v0 = p[0], v1 = p[1], v2 = p[2], v3 = p[3];
#pragma unroll
        for (int j = 0; j < 8; ++j) {
            pa[j]     = v ? (float)v0[j] : 0.f;
            pa[8 + j] = v ? (float)v1[j] : 0.f;
            pb[j]     = v ? (float)v2[j] : 0.f;
            pb[8 + j] = v ? (float)v3[j] : 0.f;
        }
    }

    half8v o[4];
#pragma unroll
    for (int c = 0; c < 16; ++c) {
        float fax = bfv[c], fay = bfv[c];
        float gax = bgv[c], gay = bgv[c];
#pragma unroll
        for (int ic = 0; ic < 16; ++ic) {
            float wf0 = wf[(c * 16 + ic) * 2 + 0];
            float wf1 = wf[(c * 16 + ic) * 2 + 1];
            float wg0 = wg[(c * 16 + ic) * 2 + 0];
            float wg1 = wg[(c * 16 + ic) * 2 + 1];
            fax = fmaf(wf0, pa[ic], fax); fax = fmaf(wf1, ra[ic], fax);
            fay = fmaf(wf0, pb[ic], fay); fay = fmaf(wf1, rb[ic], fay);
            gax = fmaf(wg0, pa[ic], gax); gax = fmaf(wg1, ra[ic], gax);
            gay = fmaf(wg0, pb[ic], gay); gay = fmaf(wg1, rb[ic], gay);
        }
        float wa = fmaf(fast_tanh(fax), fast_sigmoid(gax), ra[c]);
        float wb = fmaf(fast_tanh(fay), fast_sigmoid(gay), rb[c]);
        o[c >> 3][c & 7]       = (_Float16)wa;
        o[2 + (c >> 3)][c & 7] = (_Float16)wb;
    }

    half8v* op = (half8v*)(hOut + (size_t)t0 * 16);
    op[0] = o[0]; op[1] = o[1]; op[2] = o[2]; op[3] = o[3];
}

// ---- final: f16-MFMA skip-sum + agg + f16-MFMA logits (ds4 structure) -----
__global__ __launch_bounds__(256, 2) void final_f16(
    const _Float16* __restrict__ Hf,
    const float* __restrict__ Wsk,  const float* __restrict__ bskv,
    const float* __restrict__ Wagg, const float* __restrict__ bagg,
    const float* __restrict__ Wout, const float* __restrict__ bout,
    float* __restrict__ out)
{
    __shared__ float sv_lds[64][33];
    __shared__ unsigned short agg_bu[64 * 64];  // [pos][ic] fp16, swizzled
    __shared__ float red_m[64][5];
    __shared__ float red_s[64][5];
    __shared__ float bsum[32];

    int tid  = threadIdx.x;
    int lane = tid & 63;
    int w    = tid >> 6;
    int posG = blockIdx.x * 64;
    int b    = posG >> LOG2N;
    int nb   = posG & (NPOS - 1);

    int lr = lane & 15;
    int lg = lane >> 4;

    if (tid < 32) {
        float s = 0.f;
#pragma unroll 1
        for (int i = 0; i < 19; ++i) s += bskv[i * 32 + tid];
        bsum[tid] = s;
    }

    // ---- stage A: MFMA skip-sum over K = 19x16 (padded to 320)
    int posGlob = posG + w * 16 + lr;

    f32x4 dsk0 = {0.f, 0.f, 0.f, 0.f};
    f32x4 dsk1 = {0.f, 0.f, 0.f, 0.f};

#pragma unroll
    for (int kt = 0; kt < 10; ++kt) {
        int i   = kt * 2 + (lg >> 1);
        int ic0 = (lg & 1) * 8;
        half8v bfr = {0, 0, 0, 0, 0, 0, 0, 0};
        half8v af0 = {0, 0, 0, 0, 0, 0, 0, 0};
        half8v af1 = {0, 0, 0, 0, 0, 0, 0, 0};
        if (i < 19) {
            bfr = *(const half8v*)(Hf + (size_t)i * HFE + (size_t)posGlob * 16 + ic0);

            const float4* wp0 = (const float4*)(Wsk + (size_t)i * 512 + (0 * 16 + lr) * 16 + ic0);
            const float4* wp1 = (const float4*)(Wsk + (size_t)i * 512 + (1 * 16 + lr) * 16 + ic0);
            float4 a0 = wp0[0], a1 = wp0[1];
            float4 c0v = wp1[0], c1v = wp1[1];
            af0[0] = (_Float16)a0.x; af0[1] = (_Float16)a0.y;
            af0[2] = (_Float16)a0.z; af0[3] = (_Float16)a0.w;
            af0[4] = (_Float16)a1.x; af0[5] = (_Float16)a1.y;
            af0[6] = (_Float16)a1.z; af0[7] = (_Float16)a1.w;
            af1[0] = (_Float16)c0v.x; af1[1] = (_Float16)c0v.y;
            af1[2] = (_Float16)c0v.z; af1[3] = (_Float16)c0v.w;
            af1[4] = (_Float16)c1v.x; af1[5] = (_Float16)c1v.y;
            af1[6] = (_Float16)c1v.z; af1[7] = (_Float16)c1v.w;
        }
        dsk0 = __builtin_amdgcn_mfma_f32_16x16x32_f16(af0, bfr, dsk0, 0, 0, 0);
        dsk1 = __builtin_amdgcn_mfma_f32_16x16x32_f16(af1, bfr, dsk1, 0, 0, 0);
    }

    __syncthreads();   // bsum visible

    {
        int posL = w * 16 + lr;
#pragma unroll
        for (int r = 0; r < 4; ++r) {
            int sc0 = 0 * 16 + lg * 4 + r;
            int sc1 = 1 * 16 + lg * 4 + r;
            sv_lds[posL][sc0] = fmaxf(dsk0[r] + bsum[sc0], 0.f);
            sv_lds[posL][sc1] = fmaxf(dsk1[r] + bsum[sc1], 0.f);
        }
    }
    __syncthreads();

    // ---- stage B: agg (VALU) -> fp16 swizzled LDS
    {
        float sv[32];
#pragma unroll
        for (int sch = 0; sch < 32; ++sch) sv[sch] = sv_lds[lane][sch];

        float r16[16];
#pragma unroll
        for (int a = 0; a < 16; ++a) {
            int ac = w * 16 + a;
            float acc = bagg[ac];
#pragma unroll
            for (int sch = 0; sch < 32; ++sch)
                acc = fmaf(Wagg[ac * 32 + sch], sv[sch], acc);
            r16[a] = fmaxf(acc, 0.f);
        }
#pragma unroll
        for (int q = 0; q < 8; ++q) {
            unsigned pk = (unsigned)f16bits(r16[2 * q]) |
                          ((unsigned)f16bits(r16[2 * q + 1]) << 16);
            int icbyte = (w * 16 + 2 * q) * 2;
            int addr   = lane * 128 + (icbyte ^ ((lane & 7) << 4));
            *(unsigned*)(&agg_bu[addr >> 1]) = pk;
        }
    }
    __syncthreads();

    // ---- stage C: f16 MFMA logits
    int c0 = w * 64;
    half8v afr[4][2];
#pragma unroll
    for (int ct = 0; ct < 4; ++ct) {
#pragma unroll
        for (int kf = 0; kf < 2; ++kf) {
            int cls = c0 + ct * 16 + lr;
            int k0  = kf * 32 + lg * 8;
            const float4* wp = (const float4*)(Wout + (size_t)cls * 64 + k0);
            float4 w0 = wp[0], w1 = wp[1];
            half8v af;
            af[0] = (_Float16)w0.x; af[1] = (_Float16)w0.y;
            af[2] = (_Float16)w0.z; af[3] = (_Float16)w0.w;
            af[4] = (_Float16)w1.x; af[5] = (_Float16)w1.y;
            af[6] = (_Float16)w1.z; af[7] = (_Float16)w1.w;
            afr[ct][kf] = af;
        }
    }

    f32x4 acc[4][4];
#pragma unroll
    for (int pt = 0; pt < 4; ++pt) {
        int pos = pt * 16 + lr;
        int sw  = (pos & 7) << 4;
        const half8v* bp0 = (const half8v*)(&agg_bu[(pos * 128 + ((0 * 64 + lg * 16) ^ sw)) >> 1]);
        const half8v* bp1 = (const half8v*)(&agg_bu[(pos * 128 + ((1 * 64 + lg * 16) ^ sw)) >> 1]);
        half8v bf0 = *bp0;
        half8v bf1 = *bp1;
#pragma unroll
        for (int ct = 0; ct < 4; ++ct) {
            f32x4 c;
#pragma unroll
            for (int r = 0; r < 4; ++r) c[r] = bout[c0 + ct * 16 + lg * 4 + r];
            c = __builtin_amdgcn_mfma_f32_16x16x32_f16(afr[ct][0], bf0, c, 0, 0, 0);
            c = __builtin_amdgcn_mfma_f32_16x16x32_f16(afr[ct][1], bf1, c, 0, 0, 0);
            acc[pt][ct] = c;
        }
    }

    // ---- softmax + write (validated)
#pragma unroll
    for (int pt = 0; pt < 4; ++pt) {
        float m = -1e30f;
#pragma unroll
        for (int ct = 0; ct < 4; ++ct)
#pragma unroll
            for (int r = 0; r < 4; ++r) m = fmaxf(m, acc[pt][ct][r]);
        m = fmaxf(m, __shfl_xor(m, 16));
        m = fmaxf(m, __shfl_xor(m, 32));
        float s = 0.f;
#pragma unroll
        for (int ct = 0; ct < 4; ++ct)
#pragma unroll
            for (int r = 0; r < 4; ++r) s += __expf(acc[pt][ct][r] - m);
        s += __shfl_xor(s, 16);
        s += __shfl_xor(s, 32);
        int pos = pt * 16 + lr;
        red_m[pos][w] = m;
        red_s[pos][w] = s;
    }
    __syncthreads();

#pragma unroll
    for (int pt = 0; pt < 4; ++pt) {
        int pos = pt * 16 + lr;
        float M = fmaxf(fmaxf(red_m[pos][0], red_m[pos][1]),
                        fmaxf(red_m[pos][2], red_m[pos][3]));
        float S = 0.f;
#pragma unroll
        for (int k = 0; k < 4; ++k) S += red_s[pos][k] * __expf(red_m[pos][k] - M);
        float logZ = M + __logf(S);

        int n = nb + pos;
#pragma unroll
        for (int ct = 0; ct < 4; ++ct) {
#pragma unroll
            for (int r = 0; r < 4; ++r) {
                int cls = c0 + ct * 16 + lg * 4 + r;
                out[((size_t)(b * 256 + cls)) * NPOS + n] = acc[pt][ct][r] - logZ;
            }
        }
    }
}

// ======================================================================
// R8 fallback path (ch-major, skip-RMW, bf16 final) — safety net only
// ======================================================================
__global__ __launch_bounds__(256) void init_kernel2(
    const int* __restrict__ x_int, const float* __restrict__ W0,
    const float* __restrict__ b0, float* __restrict__ h)
{
    int t0 = (blockIdx.x * 256 + threadIdx.x) * 2;
    int n0 = t0 & (NPOS - 1);
    const float sc = 1.f / 32768.f;
    float xs0  = (n0 >= 1) ? (float)x_int[t0 - 1] * sc : 0.f;
    float xs1  = (float)x_int[t0] * sc;
    float xsp0 = (n0 >= 2) ? (float)x_int[t0 - 2] * sc : 0.f;
    float xsp1 = xs0;
#pragma unroll
    for (int c = 0; c < 16; ++c) {
        float2 o;
        o.x = xs0 + W0[c * 2 + 0] * xsp0 + W0[c * 2 + 1] * xs0 + b0[c];
        o.y = xs1 + W0[c * 2 + 0] * xsp1 + W0[c * 2 + 1] * xs1 + b0[c];
        *(float2*)(h + (size_t)c * TOTAL + t0) = o;
    }
}

__global__ __launch_bounds__(256, 2) void layer_kernel2(
    const float* __restrict__ hIn, float* __restrict__ hOut,
    float* __restrict__ skip,
    const float* __restrict__ wf, const float* __restrict__ bfv,
    const float* __restrict__ wg, const float* __restrict__ bgv,
    const float* __restrict__ wsk, const float* __restrict__ bskv,
    int d, int firstLayer)
{
    int t0 = (blockIdx.x * 256 + threadIdx.x) * 2;
    int n0 = t0 & (NPOS - 1);

    float2 hc[16], hp[16];
#pragma unroll
    for (int ic = 0; ic < 16; ++ic)
        hc[ic] = *(const float2*)(hIn + (size_t)ic * TOTAL + t0);

    if (d == 1) {
        bool v = (n0 >= 1);
        int tm = v ? (t0 - 1) : t0;
#pragma unroll
        for (int ic = 0; ic < 16; ++ic) {
            float x = hIn[(size_t)ic * TOTAL + tm];
            hp[ic].x = v ? x : 0.f;
            hp[ic].y = hc[ic].x;
        }
    } else {
        bool v = (n0 >= d);
        int tm = v ? (t0 - d) : t0;
#pragma unroll
        for (int ic = 0; ic < 16; ++ic) {
            float2 x = *(const float2*)(hIn + (size_t)ic * TOTAL + tm);
            hp[ic].x = v ? x.x : 0.f;
            hp[ic].y = v ? x.y : 0.f;
        }
    }

    float2 fa[16], ga[16];
#pragma unroll
    for (int c = 0; c < 16; ++c) {
        fa[c].x = fa[c].y = bfv[c];
        ga[c].x = ga[c].y = bgv[c];
    }
#pragma unroll
    for (int c = 0; c < 16; ++c) {
#pragma unroll
        for (int ic = 0; ic < 16; ++ic) {
            float wf0 = wf[(c * 16 + ic) * 2 + 0];
            float wf1 = wf[(c * 16 + ic) * 2 + 1];
            float wg0 = wg[(c * 16 + ic) * 2 + 0];
            float wg1 = wg[(c * 16 + ic) * 2 + 1];
            fa[c].x = fmaf(wf0, hp[ic].x, fa[c].x);
            fa[c].x = fmaf(wf1, hc[ic].x, fa[c].x);
            fa[c].y = fmaf(wf0, hp[ic].y, fa[c].y);
            fa[c].y = fmaf(wf1, hc[ic].y, fa[c].y);
            ga[c].x = fmaf(wg0, hp[ic].x, ga[c].x);
            ga[c].x = fmaf(wg1, hc[ic].x, ga[c].x);
            ga[c].y = fmaf(wg0, hp[ic].y, ga[c].y);
            ga[c].y = fmaf(wg1, hc[ic].y, ga[c].y);
        }
    }

#pragma unroll
    for (int c = 0; c < 16; ++c) {
        float2 o;
        o.x = fmaf(fast_tanh(fa[c].x), fast_sigmoid(ga[c].x), hc[c].x);
        o.y = fmaf(fast_tanh(fa[c].y), fast_sigmoid(ga[c].y), hc[c].y);
        *(float2*)(hOut + (size_t)c * TOTAL + t0) = o;
    }

#pragma unroll
    for (int sch = 0; sch < 32; ++sch) {
        float2 acc;
        acc.x = acc.y = bskv[sch];
#pragma unroll
        for (int ic = 0; ic < 16; ++ic) {
            float wv = wsk[sch * 16 + ic];
            acc.x = fmaf(wv, hc[ic].x, acc.x);
            acc.y = fmaf(wv, hc[ic].y, acc.y);
        }
        float* sp = skip + (size_t)sch * TOTAL + t0;
        if (firstLayer) {
            *(float2*)sp = acc;
        } else {
            float2 old = *(const float2*)sp;
            acc.x += old.x; acc.y += old.y;
            *(float2*)sp = acc;
        }
    }
}

__global__ __launch_bounds__(256, 2) void final_kernel(
    const float* __restrict__ skip,
    const float* __restrict__ Wagg, const float* __restrict__ bagg,
    const float* __restrict__ Wout, const float* __restrict__ bout,
    float* __restrict__ out)
{
    __shared__ unsigned short agg_bu[64 * 64];
    __shared__ float red_m[64][5];
    __shared__ float red_s[64][5];

    int tid  = threadIdx.x;
    int lane = tid & 63;
    int w    = tid >> 6;
    int posG = blockIdx.x * 64;
    int b    = posG >> LOG2N;
    int nb   = posG & (NPOS - 1);

    {
        int pos = posG + lane;
        float sv[32];
#pragma unroll
        for (int sch = 0; sch < 32; ++sch)
            sv[sch] = fmaxf(skip[(size_t)sch * TOTAL + pos], 0.f);

        float r16[16];
#pragma unroll
        for (int a = 0; a < 16; ++a) {
            int ac = w * 16 + a;
            float acc = bagg[ac];
#pragma unroll
            for (int sch = 0; sch < 32; ++sch)
                acc = fmaf(Wagg[ac * 32 + sch], sv[sch], acc);
            r16[a] = fmaxf(acc, 0.f);
        }
#pragma unroll
        for (int q = 0; q < 8; ++q) {
            unsigned pk = (unsigned)bf16rne(r16[2 * q]) |
                          ((unsigned)bf16rne(r16[2 * q + 1]) << 16);
            int icbyte = (w * 16 + 2 * q) * 2;
            int addr   = lane * 128 + (icbyte ^ ((lane & 7) << 4));
            *(unsigned*)(&agg_bu[addr >> 1]) = pk;
        }
    }
    __syncthreads();

    int lr = lane & 15;
    int lg = lane >> 4;
    int c0 = w * 64;
    short8v afr[4][2];
#pragma unroll
    for (int ct = 0; ct < 4; ++ct) {
#pragma unroll
        for (int kf = 0; kf < 2; ++kf) {
            int cls = c0 + ct * 16 + lr;
            int k0  = kf * 32 + lg * 8;
            const float4* wp = (const float4*)(Wout + (size_t)cls * 64 + k0);
            float4 w0 = wp[0], w1 = wp[1];
            short8v af;
            af[0] = (short)bf16rne(w0.x); af[1] = (short)bf16rne(w0.y);
            af[2] = (short)bf16rne(w0.z); af[3] = (short)bf16rne(w0.w);
            af[4] = (short)bf16rne(w1.x); af[5] = (short)bf16rne(w1.y);
            af[6] = (short)bf16rne(w1.z); af[7] = (short)bf16rne(w1.w);
            afr[ct][kf] = af;
        }
    }

    f32x4 acc[4][4];
#pragma unroll
    for (int pt = 0; pt < 4; ++pt) {
        int pos = pt * 16 + lr;
        int sw  = (pos & 7) << 4;
        const short8v* bp0 = (const short8v*)(&agg_bu[(pos * 128 + ((0 * 64 + lg * 16) ^ sw)) >> 1]);
        const short8v* bp1 = (const short8v*)(&agg_bu[(pos * 128 + ((1 * 64 + lg * 16) ^ sw)) >> 1]);
        short8v bf0 = *bp0;
        short8v bf1 = *bp1;
#pragma unroll
        for (int ct = 0; ct < 4; ++ct) {
            f32x4 c;
#pragma unroll
            for (int r = 0; r < 4; ++r) c[r] = bout[c0 + ct * 16 + lg * 4 + r];
            c = __builtin_amdgcn_mfma_f32_16x16x32_bf16(afr[ct][0], bf0, c, 0, 0, 0);
            c = __builtin_amdgcn_mfma_f32_16x16x32_bf16(afr[ct][1], bf1, c, 0, 0, 0);
            acc[pt][ct] = c;
        }
    }

#pragma unroll
    for (int pt = 0; pt < 4; ++pt) {
        float m = -1e30f;
#pragma unroll
        for (int ct = 0; ct < 4; ++ct)
#pragma unroll
            for (int r = 0; r < 4; ++r) m = fmaxf(m, acc[pt][ct][r]);
        m = fmaxf(m, __shfl_xor(m, 16));
        m = fmaxf(m, __shfl_xor(m, 32));
        float s = 0.f;
#pragma unroll
        for (int ct = 0; ct < 4; ++ct)
#pragma unroll
            for (int r = 0; r < 4; ++r) s += __expf(acc[pt][ct][r] - m);
        s += __shfl_xor(s, 16);
        s += __shfl_xor(s, 32);
        int pos = pt * 16 + lr;
        red_m[pos][w] = m;
        red_s[pos][w] = s;
    }
    __syncthreads();

#pragma unroll
    for (int pt = 0; pt < 4; ++pt) {
        int pos = pt * 16 + lr;
        float M = fmaxf(fmaxf(red_m[pos][0], red_m[pos][1]),
                        fmaxf(red_m[pos][2], red_m[pos][3]));
        float S = 0.f;
#pragma unroll
        for (int k = 0; k < 4; ++k) S += red_s[pos][k] * __expf(red_m[pos][k] - M);
        float logZ = M + __logf(S);

        int n = nb + pos;
#pragma unroll
        for (int ct = 0; ct < 4; ++ct) {
#pragma unroll
            for (int r = 0; r < 4; ++r) {
                int cls = c0 + ct * 16 + lg * 4 + r;
                out[((size_t)(b * 256 + cls)) * NPOS + n] = acc[pt][ct][r] - logZ;
            }
        }
    }
}

extern "C" void kernel_launch(void* const* d_in, const int* in_sizes, int n_in,
                              void* d_out, int out_size, void* d_ws, size_t ws_size,
                              hipStream_t stream)
{
    const int*   x_int = (const int*)  d_in[0];
    const float* W0    = (const float*)d_in[1];
    const float* b0    = (const float*)d_in[2];
    const float* Wf    = (const float*)d_in[3];
    const float* bfv   = (const float*)d_in[4];
    const float* Wg    = (const float*)d_in[5];
    const float* bgv   = (const float*)d_in[6];
    const float* Wsk   = (const float*)d_in[7];
    const float* bskv  = (const float*)d_in[8];
    const float* Wagg  = (const float*)d_in[9];
    const float* bagg  = (const float*)d_in[10];
    const float* Wout  = (const float*)d_in[11];
    const float* bout  = (const float*)d_in[12];
    float* out = (float*)d_out;

    const size_t needF16 = 19 * HFE * sizeof(_Float16);   // 152 MiB
    const int grid2 = TOTAL / (256 * 2);                  // 512 blocks

    if (ws_size >= needF16) {
        // ---------- fp16-ladder defer-skip path ----------
        _Float16* Hf = (_Float16*)d_ws;    // H_i at Hf + i*HFE

        init_f16<<<grid2, 256, 0, stream>>>(x_int, W0, b0, Hf);
        for (int i = 0; i < 18; ++i) {     // layer 18's h-update is dead code
            int d = 1 << ((i + 1) % 10);
            layer_f16<<<grid2, 256, 0, stream>>>(
                Hf + (size_t)i * HFE, Hf + (size_t)(i + 1) * HFE,
                Wf + (size_t)i * 512, bfv + (size_t)i * 16,
                Wg + (size_t)i * 512, bgv + (size_t)i * 16, d);
        }
        final_f16<<<TOTAL / 64, 256, 0, stream>>>(
            Hf, Wsk, bskv, Wagg, bagg, Wout, bout, out);
    } else {
        // ---------- R8 fallback (ch-major, skip-RMW) ----------
        const size_t skE = (size_t)32 * TOTAL;
        float* skipb = (float*)d_ws;
        float *hA, *hB;
        if (ws_size >= (skE + 2 * HE) * sizeof(float)) {
            hA = skipb + skE;
            hB = hA + HE;
        } else {
            hA = out + ((size_t)out_size - 2 * HE);
            hB = hA + HE;
        }

        init_kernel2<<<grid2, 256, 0, stream>>>(x_int, W0, b0, hA);
        float* hin = hA;
        float* hout = hB;
        for (int i = 0; i < 19; ++i) {
            int d = 1 << ((i + 1) % 10);
            layer_kernel2<<<grid2, 256, 0, stream>>>(
                hin, hout, skipb,
                Wf + (size_t)i * 512, bfv + (size_t)i * 16,
                Wg + (size_t)i * 512, bgv + (size_t)i * 16,
                Wsk + (size_t)i * 512, bskv + (size_t)i * 32,
                d, (i == 0) ? 1 : 0);
            float* tmp = hin; hin = hout; hout = tmp;
        }
        final_kernel<<<TOTAL / 64, 256, 0, stream>>>(
            skipb, Wagg, bagg, Wout, bout, out);
    }
}